// Round 7
// baseline (182.471 us; speedup 1.0000x reference)
//
#include <hip/hip_runtime.h>
#include <math.h>

typedef __attribute__((ext_vector_type(8))) short short8;
typedef __attribute__((ext_vector_type(4))) short shortx4;
typedef __attribute__((ext_vector_type(4))) float floatx4;

__device__ __forceinline__ float siluf(float v) { return v / (1.f + expf(-v)); }

// f32 -> bf16 bits, round-to-nearest-even
__device__ __forceinline__ short f2bf(float f) {
    unsigned u = __float_as_uint(f);
    u += 0x7fffu + ((u >> 16) & 1u);
    return (short)(u >> 16);
}

// ---------------- Fused prep kernel ----------------
// blocks 0..127: LayerNorm row b -> h_bf; c row b -> c_bf.
// blocks 128..3071: 64x64 tile transpose+convert of the 7 weight matrices -> bf16 N x K.
__global__ __launch_bounds__(256) void prep_kernel(
        const float* __restrict__ x, const float* __restrict__ ln_g,
        const float* __restrict__ ln_b, const float* __restrict__ c,
        const float* __restrict__ W_in, const float* __restrict__ W_x,
        const float* __restrict__ W_dt, const float* __restrict__ W_out,
        const float* __restrict__ W_d, const float* __restrict__ W_f,
        const float* __restrict__ W_o,
        short* __restrict__ h_bf, short* __restrict__ c_bf,
        short* __restrict__ wt_in, short* __restrict__ wt_x,
        short* __restrict__ wt_dt, short* __restrict__ wt_out,
        short* __restrict__ wt_d, short* __restrict__ wt_f,
        short* __restrict__ wt_o) {
    const int tid = threadIdx.x;
    if (blockIdx.x < 128) {
        __shared__ float sdata[256];
        int b = blockIdx.x;
        const float* xr = x + b * 1024;
        float v[4];
        float s = 0.f;
#pragma unroll
        for (int i = 0; i < 4; ++i) { v[i] = xr[tid + i * 256]; s += v[i]; }
        sdata[tid] = s; __syncthreads();
        for (int st = 128; st > 0; st >>= 1) { if (tid < st) sdata[tid] += sdata[tid + st]; __syncthreads(); }
        float mu = sdata[0] * (1.f / 1024.f);
        __syncthreads();
        float s2 = 0.f;
#pragma unroll
        for (int i = 0; i < 4; ++i) { float d = v[i] - mu; s2 += d * d; }
        sdata[tid] = s2; __syncthreads();
        for (int st = 128; st > 0; st >>= 1) { if (tid < st) sdata[tid] += sdata[tid + st]; __syncthreads(); }
        float inv = rsqrtf(sdata[0] * (1.f / 1024.f) + 1e-5f);
        short* hr = h_bf + b * 1024;
#pragma unroll
        for (int i = 0; i < 4; ++i) {
            int j = tid + i * 256;
            hr[j] = f2bf((v[i] - mu) * inv * ln_g[j] + ln_b[j]);
        }
        const float* cr = c + b * 512;
        short* cbr = c_bf + b * 512;
        cbr[tid] = f2bf(cr[tid]);
        cbr[tid + 256] = f2bf(cr[tid + 256]);
    } else {
        // ---- 64x64 tile transpose: dst[n][k] = bf16(src[k][n]) ----
        __shared__ short tl[64][68];  // row stride 136B (8B-aligned for short4)
        int t = blockIdx.x - 128;
        const float* src; short* dst; int K, N;
        if (t < 1024)      { src = W_in;  dst = wt_in;  K = 1024; N = 4096; }
        else if (t < 1792) { src = W_x;   dst = wt_x;   K = 2048; N = 1536; t -= 1024; }
        else if (t < 2048) { src = W_dt;  dst = wt_dt;  K = 512;  N = 2048; t -= 1792; }
        else if (t < 2560) { src = W_out; dst = wt_out; K = 2048; N = 1024; t -= 2048; }
        else if (t < 2688) { src = W_d;   dst = wt_d;   K = 1024; N = 512;  t -= 2560; }
        else if (t < 2816) { src = W_f;   dst = wt_f;   K = 512;  N = 1024; t -= 2688; }
        else               { src = W_o;   dst = wt_o;   K = 512;  N = 1024; t -= 2816; }
        int ntn = N >> 6;
        int k0 = (t / ntn) << 6;
        int n0 = (t % ntn) << 6;
        int rr = tid >> 4, c4 = (tid & 15) * 4;
#pragma unroll
        for (int p = 0; p < 4; ++p) {
            int r = p * 16 + rr;
            float4 v = *(const float4*)&src[(size_t)(k0 + r) * N + n0 + c4];
            shortx4 sv;
            sv[0] = f2bf(v.x); sv[1] = f2bf(v.y); sv[2] = f2bf(v.z); sv[3] = f2bf(v.w);
            *(shortx4*)&tl[r][c4] = sv;
        }
        __syncthreads();
#pragma unroll
        for (int p = 0; p < 4; ++p) {
            int n = p * 16 + rr;
            shortx4 o;
            o[0] = tl[c4 + 0][n]; o[1] = tl[c4 + 1][n];
            o[2] = tl[c4 + 2][n]; o[3] = tl[c4 + 3][n];
            *(shortx4*)&dst[(size_t)(n0 + n) * K + k0 + c4] = o;
        }
    }
}

// ---------------- full-K GEMM core, bf16 x bf16(transposed weights) ----------------
// M=128 (8 waves x 16 rows), BN=32 (2 x 16-col frags). All loads contiguous short8.
// acc[nt][r] -> C[rbase + r][n0 + nt*16 + lane15], rbase = (tid>>6)*16 + ((tid&63)>>4)*4
template<int K>
__device__ __forceinline__ void gemm32t(const short* __restrict__ A,
                                        const short* __restrict__ Bt,
                                        int n0, floatx4 acc[2]) {
    const int tid = threadIdx.x;
    const int w = tid >> 6;
    const int l = tid & 63;
    const int lane15 = l & 15;
    const int lgrp = l >> 4;
    const int r0 = w * 16 + lane15;
    const short* Ap  = A  + (size_t)r0 * K + lgrp * 8;
    const short* Bp0 = Bt + (size_t)(n0 + lane15) * K + lgrp * 8;
    const short* Bp1 = Bp0 + (size_t)16 * K;
    acc[0] = (floatx4)0.f; acc[1] = (floatx4)0.f;
    constexpr int KSTEPS = K / 32;
    short8 a_c  = *(const short8*)Ap;
    short8 b0_c = *(const short8*)Bp0;
    short8 b1_c = *(const short8*)Bp1;
#pragma unroll
    for (int s = 0; s < KSTEPS; ++s) {
        short8 a_n, b0_n, b1_n;
        if (s + 1 < KSTEPS) {
            a_n  = *(const short8*)(Ap  + (s + 1) * 32);
            b0_n = *(const short8*)(Bp0 + (s + 1) * 32);
            b1_n = *(const short8*)(Bp1 + (s + 1) * 32);
        }
        acc[0] = __builtin_amdgcn_mfma_f32_16x16x32_bf16(a_c, b0_c, acc[0], 0, 0, 0);
        acc[1] = __builtin_amdgcn_mfma_f32_16x16x32_bf16(a_c, b1_c, acc[1], 0, 0, 0);
        a_c = a_n; b0_c = b0_n; b1_c = b1_n;
    }
}

#define EPI_SETUP \
    const int tid = threadIdx.x; \
    const int lane15 = tid & 15; \
    const int rbase = (tid >> 6) * 16 + ((tid & 63) >> 4) * 4;

// ---- G1 (+e1) and G6 combined ----
__global__ __launch_bounds__(512) void g1g6_kernel(const short* __restrict__ h_bf,
                                                   const short* __restrict__ wt_in,
                                                   const short* __restrict__ c_bf,
                                                   const short* __restrict__ wt_f,
                                                   const float* __restrict__ cw3,
                                                   const float* __restrict__ cb,
                                                   float* __restrict__ u_f32,
                                                   short* __restrict__ u_bf,
                                                   float* __restrict__ sres,
                                                   float* __restrict__ gb) {
    EPI_SETUP
    floatx4 acc[2];
    if (blockIdx.x < 128) {
        int n0 = blockIdx.x * 32;
        gemm32t<1024>(h_bf, wt_in, n0, acc);
#pragma unroll
        for (int nt = 0; nt < 2; ++nt) {
            int col = n0 + nt * 16 + lane15;
#pragma unroll
            for (int r = 0; r < 4; ++r) {
                int row = rbase + r;
                float val = acc[nt][r];
                if (col < 2048) {
                    float u = siluf(val * cw3[col] + cb[col]);
                    u_f32[(size_t)row * 2048 + col] = u;
                    u_bf[(size_t)row * 2048 + col] = f2bf(u);
                } else {
                    sres[(size_t)row * 2048 + col - 2048] = siluf(val);
                }
            }
        }
    } else {
        int n0 = (blockIdx.x - 128) * 32;
        gemm32t<512>(c_bf, wt_f, n0, acc);
#pragma unroll
        for (int nt = 0; nt < 2; ++nt) {
            int col = n0 + nt * 16 + lane15;
#pragma unroll
            for (int r = 0; r < 4; ++r)
                gb[(size_t)(rbase + r) * 1024 + col] = acc[nt][r];
        }
    }
}

// ---- G2: u_bf @ W_x; cols<512 -> dr_bf, cols>=512 -> bc (Bm|Cm) ----
__global__ __launch_bounds__(512) void g2_kernel(const short* __restrict__ u_bf,
                                                 const short* __restrict__ wt_x,
                                                 short* __restrict__ dr_bf,
                                                 float* __restrict__ bc) {
    EPI_SETUP
    floatx4 acc[2];
    int n0 = blockIdx.x * 32;
    gemm32t<2048>(u_bf, wt_x, n0, acc);
#pragma unroll
    for (int nt = 0; nt < 2; ++nt) {
        int col = n0 + nt * 16 + lane15;
#pragma unroll
        for (int r = 0; r < 4; ++r) {
            int row = rbase + r;
            float val = acc[nt][r];
            if (col < 512) dr_bf[(size_t)row * 512 + col] = f2bf(val);
            else           bc[(size_t)row * 1024 + col - 512] = val;
        }
    }
}

// ---- svec[b] = dot(Bm[b], Cm[b]) ----
__global__ __launch_bounds__(256) void svec_kernel(const float* __restrict__ bc,
                                                   float* __restrict__ svec) {
    int b = blockIdx.x;
    int tid = threadIdx.x;
    __shared__ float sdata[256];
    const float* row = bc + (size_t)b * 1024;
    float s = row[tid] * row[512 + tid] + row[tid + 256] * row[768 + tid];
    sdata[tid] = s; __syncthreads();
    for (int st = 128; st > 0; st >>= 1) { if (tid < st) sdata[tid] += sdata[tid + st]; __syncthreads(); }
    if (tid == 0) svec[b] = sdata[0];
}

// ---- G3 (+e3): dr_bf @ W_dt; y = u*(softplus(val+b_dt)*svec+D)*sres -> bf16 ----
__global__ __launch_bounds__(512) void g3_kernel(const short* __restrict__ dr_bf,
                                                 const short* __restrict__ wt_dt,
                                                 const float* __restrict__ b_dt,
                                                 const float* __restrict__ svec,
                                                 const float* __restrict__ Dv,
                                                 const float* __restrict__ u_f32,
                                                 const float* __restrict__ sres,
                                                 short* __restrict__ y_bf) {
    EPI_SETUP
    floatx4 acc[2];
    int n0 = blockIdx.x * 32;
    gemm32t<512>(dr_bf, wt_dt, n0, acc);
#pragma unroll
    for (int nt = 0; nt < 2; ++nt) {
        int col = n0 + nt * 16 + lane15;
#pragma unroll
        for (int r = 0; r < 4; ++r) {
            int row = rbase + r;
            float t = acc[nt][r] + b_dt[col];
            float delta = fmaxf(t, 0.f) + log1pf(expf(-fabsf(t)));  // stable softplus
            size_t idx = (size_t)row * 2048 + col;
            y_bf[idx] = f2bf(u_f32[idx] * (delta * svec[row] + Dv[col]) * sres[idx]);
        }
    }
}

// ---- G4 (+e4): y_bf @ W_out; mamba = val + b_out + x -> bf16 ----
__global__ __launch_bounds__(512) void g4_kernel(const short* __restrict__ y_bf,
                                                 const short* __restrict__ wt_out,
                                                 const float* __restrict__ b_out,
                                                 const float* __restrict__ x,
                                                 short* __restrict__ mamba_bf) {
    EPI_SETUP
    floatx4 acc[2];
    int n0 = blockIdx.x * 32;
    gemm32t<2048>(y_bf, wt_out, n0, acc);
#pragma unroll
    for (int nt = 0; nt < 2; ++nt) {
        int col = n0 + nt * 16 + lane15;
#pragma unroll
        for (int r = 0; r < 4; ++r) {
            int row = rbase + r;
            size_t idx = (size_t)row * 1024 + col;
            mamba_bf[idx] = f2bf(acc[nt][r] + b_out[col] + x[idx]);
        }
    }
}

// ---- G5 (+e5): mamba_bf @ W_d; z = gelu(val+b_d)*(gb+b_f) FiLM -> bf16 ----
__global__ __launch_bounds__(512) void g5_kernel(const short* __restrict__ mamba_bf,
                                                 const short* __restrict__ wt_d,
                                                 const float* __restrict__ b_d,
                                                 const float* __restrict__ gb,
                                                 const float* __restrict__ b_f,
                                                 short* __restrict__ z_bf) {
    EPI_SETUP
    floatx4 acc[2];
    int n0 = blockIdx.x * 32;
    gemm32t<1024>(mamba_bf, wt_d, n0, acc);
#pragma unroll
    for (int nt = 0; nt < 2; ++nt) {
        int col = n0 + nt * 16 + lane15;
#pragma unroll
        for (int r = 0; r < 4; ++r) {
            int row = rbase + r;
            float t = acc[nt][r] + b_d[col];
            float zg = 0.5f * t * (1.f + erff(t * 0.70710678118654752f));
            float gq = gb[(size_t)row * 1024 + col] + b_f[col];
            float bb = gb[(size_t)row * 1024 + 512 + col] + b_f[512 + col];
            z_bf[(size_t)row * 512 + col] = f2bf(zg * gq + bb);
        }
    }
}

// ---- G7 (+e6): z_bf @ W_o; out = val + b_o ----
__global__ __launch_bounds__(512) void g7_kernel(const short* __restrict__ z_bf,
                                                 const short* __restrict__ wt_o,
                                                 const float* __restrict__ b_o,
                                                 float* __restrict__ out) {
    EPI_SETUP
    floatx4 acc[2];
    int n0 = blockIdx.x * 32;
    gemm32t<512>(z_bf, wt_o, n0, acc);
#pragma unroll
    for (int nt = 0; nt < 2; ++nt) {
        int col = n0 + nt * 16 + lane15;
#pragma unroll
        for (int r = 0; r < 4; ++r)
            out[(size_t)(rbase + r) * 1024 + col] = acc[nt][r] + b_o[col];
    }
}

extern "C" void kernel_launch(void* const* d_in, const int* in_sizes, int n_in,
                              void* d_out, int out_size, void* d_ws, size_t ws_size,
                              hipStream_t stream) {
    (void)in_sizes; (void)n_in; (void)out_size; (void)ws_size;
    const float* x     = (const float*)d_in[0];
    const float* c     = (const float*)d_in[1];
    const float* ln_g  = (const float*)d_in[2];
    const float* ln_b  = (const float*)d_in[3];
    const float* W_in  = (const float*)d_in[4];
    const float* convw = (const float*)d_in[5];
    const float* convb = (const float*)d_in[6];
    const float* W_x   = (const float*)d_in[7];
    const float* W_dt  = (const float*)d_in[8];
    const float* b_dt  = (const float*)d_in[9];
    // d_in[10] = A_log: provably unused (scan length 1 from h0 = 0)
    const float* Dv    = (const float*)d_in[11];
    const float* W_out = (const float*)d_in[12];
    const float* b_out = (const float*)d_in[13];
    const float* W_d   = (const float*)d_in[14];
    const float* b_d   = (const float*)d_in[15];
    const float* W_f   = (const float*)d_in[16];
    const float* b_f   = (const float*)d_in[17];
    const float* W_o   = (const float*)d_in[18];
    const float* b_o   = (const float*)d_in[19];
    float* out = (float*)d_out;

    char* ws = (char*)d_ws;
    size_t off = 0;
    auto alloc = [&](size_t bytes) { void* p = ws + off; off += (bytes + 255) & ~(size_t)255; return p; };
    // transposed bf16 weights (N x K)
    short* wt_in  = (short*)alloc((size_t)4096 * 1024 * 2);
    short* wt_x   = (short*)alloc((size_t)1536 * 2048 * 2);
    short* wt_dt  = (short*)alloc((size_t)2048 * 512 * 2);
    short* wt_out = (short*)alloc((size_t)1024 * 2048 * 2);
    short* wt_d   = (short*)alloc((size_t)512 * 1024 * 2);
    short* wt_f   = (short*)alloc((size_t)1024 * 512 * 2);
    short* wt_o   = (short*)alloc((size_t)1024 * 512 * 2);
    // activations
    short* h_bf     = (short*)alloc(128 * 1024 * 2);
    short* c_bf     = (short*)alloc(128 * 512 * 2);
    float* u_f32    = (float*)alloc((size_t)128 * 2048 * 4);
    short* u_bf     = (short*)alloc(128 * 2048 * 2);
    float* sres     = (float*)alloc((size_t)128 * 2048 * 4);
    float* gb       = (float*)alloc((size_t)128 * 1024 * 4);
    short* dr_bf    = (short*)alloc(128 * 512 * 2);
    float* bc       = (float*)alloc((size_t)128 * 1024 * 4);
    float* svec     = (float*)alloc(128 * 4);
    short* y_bf     = (short*)alloc(128 * 2048 * 2);
    short* mamba_bf = (short*)alloc(128 * 1024 * 2);
    short* z_bf     = (short*)alloc(128 * 512 * 2);

    // 1) prep: LN + c->bf16 + all weights -> bf16 transposed
    prep_kernel<<<128 + 2944, 256, 0, stream>>>(x, ln_g, ln_b, c,
                                                W_in, W_x, W_dt, W_out, W_d, W_f, W_o,
                                                h_bf, c_bf,
                                                wt_in, wt_x, wt_dt, wt_out, wt_d, wt_f, wt_o);
    // 2) G1 (+e1 fused) || G6
    g1g6_kernel<<<160, 512, 0, stream>>>(h_bf, wt_in, c_bf, wt_f, convw + 3 * 2048, convb,
                                         u_f32, u_bf, sres, gb);
    // 3) G2 (dr_bf + bc)
    g2_kernel<<<48, 512, 0, stream>>>(u_bf, wt_x, dr_bf, bc);
    // 4) svec
    svec_kernel<<<128, 256, 0, stream>>>(bc, svec);
    // 5) G3 (+e3 fused)
    g3_kernel<<<64, 512, 0, stream>>>(dr_bf, wt_dt, b_dt, svec, Dv, u_f32, sres, y_bf);
    // 6) G4 (+e4 fused)
    g4_kernel<<<32, 512, 0, stream>>>(y_bf, wt_out, b_out, x, mamba_bf);
    // 7) G5 (+e5 fused)
    g5_kernel<<<16, 512, 0, stream>>>(mamba_bf, wt_d, b_d, gb, b_f, z_bf);
    // 8) G7 (+e6 fused)
    g7_kernel<<<32, 512, 0, stream>>>(z_bf, wt_o, b_o, out);
}

// Round 8
// 99.221 us; speedup vs baseline: 1.8390x; 1.8390x over previous
//
#include <hip/hip_runtime.h>
#include <math.h>

typedef __attribute__((ext_vector_type(8))) short short8;
typedef __attribute__((ext_vector_type(4))) short shortx4;
typedef __attribute__((ext_vector_type(4))) float floatx4;

__device__ __forceinline__ float siluf(float v) { return v / (1.f + expf(-v)); }

__device__ __forceinline__ short f2bf(float f) {
    unsigned u = __float_as_uint(f);
    u += 0x7fffu + ((u >> 16) & 1u);
    return (short)(u >> 16);
}

// slice strides
#define SL1 ((size_t)128 * 4096)  // xz
#define SLG ((size_t)128 * 1024)  // gb
#define SL2 ((size_t)128 * 1536)  // xdbl
#define SLD ((size_t)128 * 2048)  // dacc
#define SLM ((size_t)128 * 1024)  // mo
#define SLZ ((size_t)128 * 512)   // zd
#define SLO ((size_t)128 * 1024)  // out_p

// ---------------- prep: LN (blocks 0..127) + weight transpose->bf16 NxK (blocks 128..3071) ----------------
__global__ __launch_bounds__(256) void prep_kernel(
        const float* __restrict__ x, const float* __restrict__ ln_g,
        const float* __restrict__ ln_b, const float* __restrict__ c,
        const float* __restrict__ W_in, const float* __restrict__ W_x,
        const float* __restrict__ W_dt, const float* __restrict__ W_out,
        const float* __restrict__ W_d, const float* __restrict__ W_f,
        const float* __restrict__ W_o,
        short* __restrict__ h_bf, short* __restrict__ c_bf,
        short* __restrict__ wt_in, short* __restrict__ wt_x,
        short* __restrict__ wt_dt, short* __restrict__ wt_out,
        short* __restrict__ wt_d, short* __restrict__ wt_f,
        short* __restrict__ wt_o) {
    const int tid = threadIdx.x;
    if (blockIdx.x < 128) {
        __shared__ float sdata[256];
        int b = blockIdx.x;
        const float* xr = x + b * 1024;
        float v[4];
        float s = 0.f;
#pragma unroll
        for (int i = 0; i < 4; ++i) { v[i] = xr[tid + i * 256]; s += v[i]; }
        sdata[tid] = s; __syncthreads();
        for (int st = 128; st > 0; st >>= 1) { if (tid < st) sdata[tid] += sdata[tid + st]; __syncthreads(); }
        float mu = sdata[0] * (1.f / 1024.f);
        __syncthreads();
        float s2 = 0.f;
#pragma unroll
        for (int i = 0; i < 4; ++i) { float d = v[i] - mu; s2 += d * d; }
        sdata[tid] = s2; __syncthreads();
        for (int st = 128; st > 0; st >>= 1) { if (tid < st) sdata[tid] += sdata[tid + st]; __syncthreads(); }
        float inv = rsqrtf(sdata[0] * (1.f / 1024.f) + 1e-5f);
        short* hr = h_bf + b * 1024;
#pragma unroll
        for (int i = 0; i < 4; ++i) {
            int j = tid + i * 256;
            hr[j] = f2bf((v[i] - mu) * inv * ln_g[j] + ln_b[j]);
        }
        const float* cr = c + b * 512;
        short* cbr = c_bf + b * 512;
        cbr[tid] = f2bf(cr[tid]);
        cbr[tid + 256] = f2bf(cr[tid + 256]);
    } else {
        __shared__ short tl[64][68];
        int t = blockIdx.x - 128;
        const float* src; short* dst; int K, N;
        if (t < 1024)      { src = W_in;  dst = wt_in;  K = 1024; N = 4096; }
        else if (t < 1792) { src = W_x;   dst = wt_x;   K = 2048; N = 1536; t -= 1024; }
        else if (t < 2048) { src = W_dt;  dst = wt_dt;  K = 512;  N = 2048; t -= 1792; }
        else if (t < 2560) { src = W_out; dst = wt_out; K = 2048; N = 1024; t -= 2048; }
        else if (t < 2688) { src = W_d;   dst = wt_d;   K = 1024; N = 512;  t -= 2560; }
        else if (t < 2816) { src = W_f;   dst = wt_f;   K = 512;  N = 1024; t -= 2688; }
        else               { src = W_o;   dst = wt_o;   K = 512;  N = 1024; t -= 2816; }
        int ntn = N >> 6;
        int k0 = (t / ntn) << 6;
        int n0 = (t % ntn) << 6;
        int rr = tid >> 4, c4 = (tid & 15) * 4;
#pragma unroll
        for (int p = 0; p < 4; ++p) {
            int r = p * 16 + rr;
            float4 v = *(const float4*)&src[(size_t)(k0 + r) * N + n0 + c4];
            shortx4 sv;
            sv[0] = f2bf(v.x); sv[1] = f2bf(v.y); sv[2] = f2bf(v.z); sv[3] = f2bf(v.w);
            *(shortx4*)&tl[r][c4] = sv;
        }
        __syncthreads();
#pragma unroll
        for (int p = 0; p < 4; ++p) {
            int n = p * 16 + rr;
            shortx4 o;
            o[0] = tl[c4 + 0][n]; o[1] = tl[c4 + 1][n];
            o[2] = tl[c4 + 2][n]; o[3] = tl[c4 + 3][n];
            *(shortx4*)&dst[(size_t)(n0 + n) * K + k0 + c4] = o;
        }
    }
}

// ---- A-fragment loader ----
// MODE 0: bf16 A (lda in shorts)
// MODE 1: sum NS f32 slices (stride SL), convert
// MODE 2: sum NS f32 slices + aux0[j] + aux1[r*lda+j], convert
template<int MODE, int NS>
__device__ __forceinline__ short8 a_frag(const void* __restrict__ A, int lda, size_t SL,
                                         int r, int j0,
                                         const float* __restrict__ aux0,
                                         const float* __restrict__ aux1) {
    if constexpr (MODE == 0) {
        return *(const short8*)((const short*)A + (size_t)r * lda + j0);
    } else {
        const float* Af = (const float*)A;
        size_t base = (size_t)r * lda + j0;
        short8 sv;
#pragma unroll
        for (int i = 0; i < 8; ++i) {
            float t = 0.f;
#pragma unroll
            for (int s = 0; s < NS; ++s) t += Af[(size_t)s * SL + base + i];
            if constexpr (MODE == 2) t += aux0[j0 + i] + aux1[base + i];
            sv[i] = f2bf(t);
        }
        return sv;
    }
}

// ---- GEMM body: 256 threads = 4 waves; wave w rows [w*32,w*32+32); BN=32 at n0; K-chunk at k0 ----
template<int MODE, int NS, int KSTEPS>
__device__ __forceinline__ void gemm_body(const void* __restrict__ A, int lda, size_t SL,
                                          const float* __restrict__ aux0,
                                          const float* __restrict__ aux1,
                                          const short* __restrict__ Bt, int K,
                                          float* __restrict__ Cs, int ldc,
                                          int n0, int k0) {
    const int tid = threadIdx.x;
    const int w = tid >> 6;
    const int l = tid & 63;
    const int lane15 = l & 15;
    const int lgrp = l >> 4;
    const int r0 = w * 32 + lane15;
    const short* Bp0 = Bt + (size_t)(n0 + lane15) * K + k0 + lgrp * 8;
    const short* Bp1 = Bp0 + (size_t)16 * K;

    floatx4 acc[2][2];
#pragma unroll
    for (int i = 0; i < 2; ++i)
#pragma unroll
        for (int j = 0; j < 2; ++j) acc[i][j] = (floatx4)0.f;

#pragma unroll
    for (int s = 0; s < KSTEPS; ++s) {
        int j0 = k0 + s * 32 + lgrp * 8;
        short8 a0 = a_frag<MODE, NS>(A, lda, SL, r0, j0, aux0, aux1);
        short8 a1 = a_frag<MODE, NS>(A, lda, SL, r0 + 16, j0, aux0, aux1);
        short8 b0 = *(const short8*)(Bp0 + s * 32);
        short8 b1 = *(const short8*)(Bp1 + s * 32);
        acc[0][0] = __builtin_amdgcn_mfma_f32_16x16x32_bf16(a0, b0, acc[0][0], 0, 0, 0);
        acc[0][1] = __builtin_amdgcn_mfma_f32_16x16x32_bf16(a0, b1, acc[0][1], 0, 0, 0);
        acc[1][0] = __builtin_amdgcn_mfma_f32_16x16x32_bf16(a1, b0, acc[1][0], 0, 0, 0);
        acc[1][1] = __builtin_amdgcn_mfma_f32_16x16x32_bf16(a1, b1, acc[1][1], 0, 0, 0);
    }
    const int rbase = w * 32 + lgrp * 4;
#pragma unroll
    for (int mf = 0; mf < 2; ++mf)
#pragma unroll
        for (int nt = 0; nt < 2; ++nt)
#pragma unroll
            for (int r = 0; r < 4; ++r)
                Cs[(size_t)(rbase + mf * 16 + r) * ldc + n0 + nt * 16 + lane15] = acc[mf][nt][r];
}

// ---- G1 (256 blk) + G6 (64 blk) ----
__global__ __launch_bounds__(256) void g1g6_kernel(const short* __restrict__ h_bf,
                                                   const short* __restrict__ wt_in,
                                                   const short* __restrict__ c_bf,
                                                   const short* __restrict__ wt_f,
                                                   float* __restrict__ xz_p,
                                                   float* __restrict__ gb_p) {
    int bid = blockIdx.x;
    if (bid < 256) {
        int nb = bid >> 1, ks = bid & 1;
        gemm_body<0, 0, 16>(h_bf, 1024, 0, nullptr, nullptr, wt_in, 1024,
                            xz_p + (size_t)ks * SL1, 4096, nb * 32, ks * 512);
    } else {
        int t = bid - 256;
        int nb = t >> 1, ks = t & 1;
        gemm_body<0, 0, 8>(c_bf, 512, 0, nullptr, nullptr, wt_f, 512,
                           gb_p + (size_t)ks * SLG, 1024, nb * 32, ks * 256);
    }
}

// ---- e1: u = silu(conv(sum xz)), sres = silu(res) ----
__global__ __launch_bounds__(256) void e1_kernel(const float* __restrict__ xz_p,
                                                 const float* __restrict__ cw3,
                                                 const float* __restrict__ cb,
                                                 float* __restrict__ u_f32,
                                                 short* __restrict__ u_bf,
                                                 float* __restrict__ sres) {
#pragma unroll
    for (int q = 0; q < 4; ++q) {
        int i = blockIdx.x * 1024 + q * 256 + threadIdx.x;  // 128*4096
        int b = i >> 12, j = i & 4095;
        float val = xz_p[i] + xz_p[SL1 + i];
        if (j < 2048) {
            float u = siluf(val * cw3[j] + cb[j]);
            u_f32[b * 2048 + j] = u;
            u_bf[b * 2048 + j] = f2bf(u);
        } else {
            sres[b * 2048 + (j - 2048)] = siluf(val);
        }
    }
}

// ---- G2: u_bf @ wt_x -> 4 xdbl slices (192 blk) ----
__global__ __launch_bounds__(256) void g2_kernel(const short* __restrict__ u_bf,
                                                 const short* __restrict__ wt_x,
                                                 float* __restrict__ xd_p) {
    int nb = blockIdx.x >> 2, ks = blockIdx.x & 3;
    gemm_body<0, 0, 16>(u_bf, 2048, 0, nullptr, nullptr, wt_x, 2048,
                        xd_p + (size_t)ks * SL2, 1536, nb * 32, ks * 512);
}

// ---- G3: dr(sum 4 xdbl slices) @ wt_dt -> 2 dacc slices (128 blk) ----
__global__ __launch_bounds__(256) void g3_kernel(const float* __restrict__ xd_p,
                                                 const short* __restrict__ wt_dt,
                                                 float* __restrict__ dacc_p) {
    int nb = blockIdx.x >> 1, ks = blockIdx.x & 1;
    gemm_body<1, 4, 8>(xd_p, 1536, SL2, nullptr, nullptr, wt_dt, 512,
                       dacc_p + (size_t)ks * SLD, 2048, nb * 32, ks * 256);
}

// ---- e3: per-row svec + y = u*(softplus(sum dacc+b_dt)*svec + D)*sres -> bf16 ----
__global__ __launch_bounds__(256) void e3_kernel(const float* __restrict__ xd_p,
                                                 const float* __restrict__ dacc_p,
                                                 const float* __restrict__ b_dt,
                                                 const float* __restrict__ u_f32,
                                                 const float* __restrict__ sres,
                                                 const float* __restrict__ Dv,
                                                 short* __restrict__ y_bf) {
    int row = blockIdx.x;
    int tid = threadIdx.x;
    __shared__ float sdata[256];
    float s = 0.f;
#pragma unroll
    for (int q = 0; q < 2; ++q) {
        int n = tid + q * 256;
        float bm = 0.f, cm = 0.f;
#pragma unroll
        for (int sl = 0; sl < 4; ++sl) {
            bm += xd_p[(size_t)sl * SL2 + (size_t)row * 1536 + 512 + n];
            cm += xd_p[(size_t)sl * SL2 + (size_t)row * 1536 + 1024 + n];
        }
        s += bm * cm;
    }
    sdata[tid] = s; __syncthreads();
    for (int st = 128; st > 0; st >>= 1) { if (tid < st) sdata[tid] += sdata[tid + st]; __syncthreads(); }
    float svec = sdata[0];
#pragma unroll
    for (int q = 0; q < 8; ++q) {
        int j = tid + q * 256;
        size_t idx = (size_t)row * 2048 + j;
        float t = b_dt[j] + dacc_p[idx] + dacc_p[SLD + idx];
        float delta = fmaxf(t, 0.f) + log1pf(expf(-fabsf(t)));
        y_bf[idx] = f2bf(u_f32[idx] * (delta * svec + Dv[j]) * sres[idx]);
    }
}

// ---- G4: y_bf @ wt_out -> 4 mo slices (128 blk) ----
__global__ __launch_bounds__(256) void g4_kernel(const short* __restrict__ y_bf,
                                                 const short* __restrict__ wt_out,
                                                 float* __restrict__ mo_p) {
    int nb = blockIdx.x >> 2, ks = blockIdx.x & 3;
    gemm_body<0, 0, 16>(y_bf, 2048, 0, nullptr, nullptr, wt_out, 2048,
                        mo_p + (size_t)ks * SLM, 1024, nb * 32, ks * 512);
}

// ---- G5: (sum mo + b_out + x) @ wt_d -> 8 zd slices (128 blk) ----
__global__ __launch_bounds__(256) void g5_kernel(const float* __restrict__ mo_p,
                                                 const float* __restrict__ b_out,
                                                 const float* __restrict__ x,
                                                 const short* __restrict__ wt_d,
                                                 float* __restrict__ zd_p) {
    int nb = blockIdx.x >> 3, ks = blockIdx.x & 7;
    gemm_body<2, 4, 4>(mo_p, 1024, SLM, b_out, x, wt_d, 1024,
                       zd_p + (size_t)ks * SLZ, 512, nb * 32, ks * 128);
}

// ---- e5: z = gelu(sum zd + b_d) * (sum gb + b_f) + (.) -> bf16 ----
__global__ __launch_bounds__(256) void e5_kernel(const float* __restrict__ zd_p,
                                                 const float* __restrict__ b_d,
                                                 const float* __restrict__ gb_p,
                                                 const float* __restrict__ b_f,
                                                 short* __restrict__ z_bf) {
#pragma unroll
    for (int q = 0; q < 4; ++q) {
        int i = blockIdx.x * 1024 + q * 256 + threadIdx.x;  // 128*512
        int row = i >> 9, n = i & 511;
        float t = b_d[n];
#pragma unroll
        for (int sl = 0; sl < 8; ++sl) t += zd_p[(size_t)sl * SLZ + i];
        float zg = 0.5f * t * (1.f + erff(t * 0.70710678118654752f));
        float gq = b_f[n], bb = b_f[512 + n];
#pragma unroll
        for (int sl = 0; sl < 2; ++sl) {
            gq += gb_p[(size_t)sl * SLG + (size_t)row * 1024 + n];
            bb += gb_p[(size_t)sl * SLG + (size_t)row * 1024 + 512 + n];
        }
        z_bf[i] = f2bf(zg * gq + bb);
    }
}

// ---- G7: z_bf @ wt_o -> 4 out slices (128 blk) ----
__global__ __launch_bounds__(256) void g7_kernel(const short* __restrict__ z_bf,
                                                 const short* __restrict__ wt_o,
                                                 float* __restrict__ ou_p) {
    int nb = blockIdx.x >> 2, ks = blockIdx.x & 3;
    gemm_body<0, 0, 4>(z_bf, 512, 0, nullptr, nullptr, wt_o, 512,
                       ou_p + (size_t)ks * SLO, 1024, nb * 32, ks * 128);
}

// ---- e6: out = sum 4 slices + b_o ----
__global__ __launch_bounds__(256) void e6_kernel(const float* __restrict__ ou_p,
                                                 const float* __restrict__ b_o,
                                                 float* __restrict__ out) {
#pragma unroll
    for (int q = 0; q < 4; ++q) {
        int i = blockIdx.x * 1024 + q * 256 + threadIdx.x;  // 128*1024
        int j = i & 1023;
        float t = b_o[j];
#pragma unroll
        for (int sl = 0; sl < 4; ++sl) t += ou_p[(size_t)sl * SLO + i];
        out[i] = t;
    }
}

extern "C" void kernel_launch(void* const* d_in, const int* in_sizes, int n_in,
                              void* d_out, int out_size, void* d_ws, size_t ws_size,
                              hipStream_t stream) {
    (void)in_sizes; (void)n_in; (void)out_size; (void)ws_size;
    const float* x     = (const float*)d_in[0];
    const float* c     = (const float*)d_in[1];
    const float* ln_g  = (const float*)d_in[2];
    const float* ln_b  = (const float*)d_in[3];
    const float* W_in  = (const float*)d_in[4];
    const float* convw = (const float*)d_in[5];
    const float* convb = (const float*)d_in[6];
    const float* W_x   = (const float*)d_in[7];
    const float* W_dt  = (const float*)d_in[8];
    const float* b_dt  = (const float*)d_in[9];
    // d_in[10] = A_log: unused (scan length 1 from h0 = 0)
    const float* Dv    = (const float*)d_in[11];
    const float* W_out = (const float*)d_in[12];
    const float* b_out = (const float*)d_in[13];
    const float* W_d   = (const float*)d_in[14];
    const float* b_d   = (const float*)d_in[15];
    const float* W_f   = (const float*)d_in[16];
    const float* b_f   = (const float*)d_in[17];
    const float* W_o   = (const float*)d_in[18];
    const float* b_o   = (const float*)d_in[19];
    float* out = (float*)d_out;

    char* ws = (char*)d_ws;
    size_t off = 0;
    auto alloc = [&](size_t bytes) { void* p = ws + off; off += (bytes + 255) & ~(size_t)255; return p; };
    short* wt_in  = (short*)alloc((size_t)4096 * 1024 * 2);
    short* wt_x   = (short*)alloc((size_t)1536 * 2048 * 2);
    short* wt_dt  = (short*)alloc((size_t)2048 * 512 * 2);
    short* wt_out = (short*)alloc((size_t)1024 * 2048 * 2);
    short* wt_d   = (short*)alloc((size_t)512 * 1024 * 2);
    short* wt_f   = (short*)alloc((size_t)1024 * 512 * 2);
    short* wt_o   = (short*)alloc((size_t)1024 * 512 * 2);
    float* xz_p   = (float*)alloc(2 * SL1 * 4);
    float* gb_p   = (float*)alloc(2 * SLG * 4);
    float* xd_p   = (float*)alloc(4 * SL2 * 4);
    float* dacc_p = (float*)alloc(2 * SLD * 4);
    float* mo_p   = (float*)alloc(4 * SLM * 4);
    float* zd_p   = (float*)alloc(8 * SLZ * 4);
    float* ou_p   = (float*)alloc(4 * SLO * 4);
    short* h_bf   = (short*)alloc(128 * 1024 * 2);
    short* c_bf   = (short*)alloc(128 * 512 * 2);
    float* u_f32  = (float*)alloc((size_t)128 * 2048 * 4);
    short* u_bf   = (short*)alloc(128 * 2048 * 2);
    float* sres   = (float*)alloc((size_t)128 * 2048 * 4);
    short* y_bf   = (short*)alloc(128 * 2048 * 2);
    short* z_bf   = (short*)alloc(128 * 512 * 2);

    prep_kernel<<<3072, 256, 0, stream>>>(x, ln_g, ln_b, c,
                                          W_in, W_x, W_dt, W_out, W_d, W_f, W_o,
                                          h_bf, c_bf,
                                          wt_in, wt_x, wt_dt, wt_out, wt_d, wt_f, wt_o);
    g1g6_kernel<<<320, 256, 0, stream>>>(h_bf, wt_in, c_bf, wt_f, xz_p, gb_p);
    e1_kernel<<<512, 256, 0, stream>>>(xz_p, convw + 3 * 2048, convb, u_f32, u_bf, sres);
    g2_kernel<<<192, 256, 0, stream>>>(u_bf, wt_x, xd_p);
    g3_kernel<<<128, 256, 0, stream>>>(xd_p, wt_dt, dacc_p);
    e3_kernel<<<128, 256, 0, stream>>>(xd_p, dacc_p, b_dt, u_f32, sres, Dv, y_bf);
    g4_kernel<<<128, 256, 0, stream>>>(y_bf, wt_out, mo_p);
    g5_kernel<<<128, 256, 0, stream>>>(mo_p, b_out, x, wt_d, zd_p);
    e5_kernel<<<64, 256, 0, stream>>>(zd_p, b_d, gb_p, b_f, z_bf);
    g7_kernel<<<128, 256, 0, stream>>>(z_bf, wt_o, ou_p);
    e6_kernel<<<128, 256, 0, stream>>>(ou_p, b_o, out);
}